// Round 14
// baseline (140.597 us; speedup 1.0000x reference)
//
#include <hip/hip_runtime.h>
#include <math.h>

// Problem constants
#define DD 256
#define HH 8
#define AA 32
#define SS 512
#define BB 2
constexpr float BCONST      = 0.9f;
constexpr float ONE_MINUS_B = 0.1f;
constexpr float EPSF        = 1e-10f;
constexpr float SCALEF      = 0.0625f;   // 1/sqrt(256), exact power of 2
constexpr float FLTMAX      = 3.402823466e38f;

// Workspace layout (float offsets)
#define OFF_QKV    0
#define OFF_VP     786432
#define OFF_EW     1048576
#define OFF_PMIN   1310720
#define OFF_PMAX   1318912
#define OFF_VMIN   1327104
#define OFF_VRANGE 1327616
#define OFF_P      1328128
#define OFF_CTR    1328384   // 2 x u32 barrier counters (memset 0 per launch)

// Swizzled chunk buffer: row-major LD=32 floats, bank-quad ^= (row>>2)&7.
#define KB4(buf, row, col4) \
  (&(buf)[((row) << 5) | ((((col4) >> 2) ^ (((row) >> 2) & 7)) << 2)])

// ---------------------------------------------------------------------------
// Device-scope grid barrier for a 256-block (=CU count), 1-block/CU kernel.
// All blocks are co-resident (LDS 133 KB/block forces 1/CU; grid == #CUs),
// so the spin cannot deadlock. Release: threadfence + atomicAdd; acquire:
// spin on atomic load, then threadfence.
// ---------------------------------------------------------------------------
__device__ __forceinline__ void gbar(unsigned int* c, unsigned int tgt) {
  __syncthreads();
  if (threadIdx.x == 0) {
    __threadfence();
    atomicAdd(c, 1u);
    while (atomicAdd(c, 0u) < tgt) __builtin_amdgcn_s_sleep(4);
    __threadfence();
  }
  __syncthreads();
}

// ---------------------------------------------------------------------------
// Fused Q|K|V projection (R12-proven 256-thread config): 32x64 tiles,
// 2x4 micro-tile, grid 32x12 = 384 blocks (6 waves/CU interleaved — R13
// showed 2-wave blocks starve on prefetch latency).
// V-column blocks (j0>=512) write per-row-tile min/max partials.
// ---------------------------------------------------------------------------
__global__ __launch_bounds__(256) void gemm_qkv(
    const float* __restrict__ A, const float* __restrict__ B0,
    const float* __restrict__ B1, int nsplit,
    float* __restrict__ C, int ldc, int K, int lda,
    float* __restrict__ pminP, float* __restrict__ pmaxP) {
  constexpr int TM = 32, TN = 64, RM = 2, RN = 4;
  constexpr int LDT = 36;
  constexpr int CG  = TN / RN;
  constexpr int NA  = 1, NB = 2;
  __shared__ float As[TM][LDT];
  __shared__ float Bs[TN][LDT];
  const int i0 = blockIdx.x * TM;
  const int j0 = blockIdx.y * TN;
  const float* Bsrc = (j0 < nsplit) ? (B0 + (size_t)j0 * K)
                                    : (B1 + (size_t)(j0 - nsplit) * K);
  const int t  = threadIdx.x;
  const int lr = t >> 3;
  const int lc = (t & 7) << 2;
  const int tx = t % CG, ty = t / CG;

  float4 pa[NA], pb[NB];
#pragma unroll
  for (int u = 0; u < NA; ++u)
    pa[u] = *(const float4*)(A + (size_t)(i0 + lr + 32 * u) * lda + lc);
#pragma unroll
  for (int u = 0; u < NB; ++u)
    pb[u] = *(const float4*)(Bsrc + (size_t)(lr + 32 * u) * K + lc);

  float acc[RM][RN] = {};
  for (int k0 = 0; k0 < K; k0 += 32) {
    __syncthreads();
#pragma unroll
    for (int u = 0; u < NA; ++u) *(float4*)&As[lr + 32 * u][lc] = pa[u];
#pragma unroll
    for (int u = 0; u < NB; ++u) *(float4*)&Bs[lr + 32 * u][lc] = pb[u];
    __syncthreads();
    if (k0 + 32 < K) {
#pragma unroll
      for (int u = 0; u < NA; ++u)
        pa[u] = *(const float4*)(A + (size_t)(i0 + lr + 32 * u) * lda + k0 + 32 + lc);
#pragma unroll
      for (int u = 0; u < NB; ++u)
        pb[u] = *(const float4*)(Bsrc + (size_t)(lr + 32 * u) * K + k0 + 32 + lc);
    }
#pragma unroll
    for (int kk = 0; kk < 32; kk += 4) {
      float4 af[RM], bf[RN];
#pragma unroll
      for (int r = 0; r < RM; ++r) af[r] = *(const float4*)&As[ty * RM + r][kk];
#pragma unroll
      for (int c = 0; c < RN; ++c) bf[c] = *(const float4*)&Bs[tx + CG * c][kk];
#pragma unroll
      for (int r = 0; r < RM; ++r)
#pragma unroll
        for (int c = 0; c < RN; ++c)
          acc[r][c] += af[r].x * bf[c].x + af[r].y * bf[c].y +
                       af[r].z * bf[c].z + af[r].w * bf[c].w;
    }
  }
#pragma unroll
  for (int r = 0; r < RM; ++r)
#pragma unroll
    for (int c = 0; c < RN; ++c)
      C[(size_t)(i0 + ty * RM + r) * ldc + j0 + tx + CG * c] = acc[r][c];

  if (j0 >= 512) {                     // V-column min/max partials
    __syncthreads();
    float* mnb = &As[0][0];
    float* mxb = &Bs[0][0];
#pragma unroll
    for (int c = 0; c < RN; ++c) {
      float mn = acc[0][c], mx = acc[0][c];
#pragma unroll
      for (int r = 1; r < RM; ++r) {
        mn = fminf(mn, acc[r][c]);
        mx = fmaxf(mx, acc[r][c]);
      }
      mnb[(tx + CG * c) * 17 + ty] = mn;
      mxb[(tx + CG * c) * 17 + ty] = mx;
    }
    __syncthreads();
    if (t < TN) {
      float mn = mnb[t * 17], mx = mxb[t * 17];
#pragma unroll
      for (int i = 1; i < 16; ++i) {
        mn = fminf(mn, mnb[t * 17 + i]);
        mx = fmaxf(mx, mxb[t * 17 + i]);
      }
      const int bx = i0 >> 5;          // row-tile 0..31 (16 per batch)
      pminP[bx * 256 + (j0 - 512) + t] = mn;
      pmaxP[bx * 256 + (j0 - 512) + t] = mx;
    }
  }
}

// ---------------------------------------------------------------------------
// MEGA kernel: vpk -> [grid barrier] -> attn (R12 body) -> [grid barrier]
// -> output projection. 256 blocks x 256 threads, 1 block/CU (LDS-forced),
// replacing 3 kernel launches with 2 atomic barriers.
// ---------------------------------------------------------------------------
__global__ __launch_bounds__(256, 1) void mega(
    const float* __restrict__ qkv, const float* __restrict__ pminP,
    const float* __restrict__ pmaxP, const float* __restrict__ p_param,
    float* __restrict__ vp, float* __restrict__ vminw,
    float* __restrict__ vrangew, float* __restrict__ pw,
    float* __restrict__ ew, const float* __restrict__ WOUT,
    float* __restrict__ out, unsigned int* __restrict__ ctr) {
  __shared__ float qs[32][36];         // attn q tile / outproj As
  __shared__ float sc[32 * 516];       // attn scores / outproj Bs (aliased)
  __shared__ float kb[512 * 32];       // attn K/VP panel (reused: part)
  __shared__ float red[32];            // attn row sums
  const int bid = blockIdx.x;
  const int t   = threadIdx.x;

  // ======== Phase B: vpk — 4 rows per block; min/max hoisted once ========
  {
    const int u0 = bid * 4;            // first row unit (b*512+s)
    const int b  = u0 >> 9;            // 0..127 -> b=0, 128..255 -> b=1
    const int d  = t;
    float mn = pminP[(b * 16) * 256 + d];
    float mx = pmaxP[(b * 16) * 256 + d];
#pragma unroll
    for (int c = 1; c < 16; ++c) {
      mn = fminf(mn, pminP[(b * 16 + c) * 256 + d]);
      mx = fmaxf(mx, pmaxP[(b * 16 + c) * 256 + d]);
    }
    float p = 50000.0f * tanhf(0.005f * p_param[d]) + 1.0f;
    if (p == 0.0f) p = 0.0001f;
    const float range = mx - mn + EPSF;
#pragma unroll
    for (int i = 0; i < 4; ++i) {
      const float v  = qkv[((size_t)(u0 + i)) * 768 + 512 + d];
      const float vn = (ONE_MINUS_B * (v - mn)) / range + BCONST;
      vp[(size_t)(u0 + i) * 256 + d] = expm1f(p * logf(vn));
    }
    if ((bid & 127) == 0) {            // first unit has s == 0
      vminw[b * 256 + d] = mn;
      vrangew[b * 256 + d] = range;
    }
    if (bid == 0) pw[d] = p;
  }
  gbar(ctr + 0, 256u);

  // ======== Phase C: attention (R12-proven body) ========
  {
    const int q0g = (bid & 15) * 32;   // blockIdx.x-equivalent (fastest)
    const int bh  = bid >> 4;
    const int b   = bh >> 3, h = bh & 7;
    const int srow = t >> 3, scol4 = (t & 7) << 2;

    {                                  // q tile, fold in SCALE
      const int q = t >> 3, c4 = (t & 7) << 2;
      float4 qv = *(const float4*)(qkv + ((size_t)(b * 512 + q0g + q)) * 768 + h * 32 + c4);
      qv.x *= SCALEF; qv.y *= SCALEF; qv.z *= SCALEF; qv.w *= SCALEF;
      *(float4*)&qs[q][c4] = qv;
    }
#pragma unroll 8
    for (int u = 0; u < 16; ++u) {     // stage FULL K panel
      const int r = srow + 32 * u;
      float4 v = *(const float4*)(qkv + ((size_t)(b * 512 + r)) * 768 + 256 + h * 32 + scol4);
      *(float4*)KB4(kb, r, scol4) = v;
    }
    __syncthreads();

    // Phase 1: scores + inline softmax (8q x 8k; wave-uniform q group)
    {
      const int qgw = t >> 6;
      const int kg  = t & 63;
      float s8[8][8] = {};
#pragma unroll 2
      for (int kk = 0; kk < 32; kk += 4) {
        float4 qf[8], kf1[4], kf2[4];
#pragma unroll
        for (int r = 0; r < 8; ++r) qf[r] = *(const float4*)&qs[qgw + 4 * r][kk];
#pragma unroll
        for (int c = 0; c < 4; ++c) {
          kf1[c] = *(const float4*)KB4(kb, kg * 4 + c, kk);
          kf2[c] = *(const float4*)KB4(kb, 256 + kg * 4 + c, kk);
        }
#pragma unroll
        for (int r = 0; r < 8; ++r)
#pragma unroll
          for (int c = 0; c < 4; ++c) {
            s8[r][c]     += qf[r].x * kf1[c].x + qf[r].y * kf1[c].y +
                            qf[r].z * kf1[c].z + qf[r].w * kf1[c].w;
            s8[r][4 + c] += qf[r].x * kf2[c].x + qf[r].y * kf2[c].y +
                            qf[r].z * kf2[c].z + qf[r].w * kf2[c].w;
          }
      }
      float rs[8];
#pragma unroll
      for (int r = 0; r < 8; ++r) {
        float s = 0.f;
#pragma unroll
        for (int c = 0; c < 8; ++c) {
          s8[r][c] = __expf(s8[r][c]);   // |score| < ~3: no max needed
          s += s8[r][c];
        }
        rs[r] = s;
      }
#pragma unroll
      for (int m = 1; m < 64; m <<= 1)
#pragma unroll
        for (int r = 0; r < 8; ++r) rs[r] += __shfl_xor(rs[r], m);
      if ((t & 63) == 0)
#pragma unroll
        for (int r = 0; r < 8; ++r) red[qgw + 4 * r] = rs[r];
#pragma unroll
      for (int r = 0; r < 8; ++r) {
        const int rq = qgw + 4 * r;
        *(float4*)&sc[rq * 516 + kg * 4] =
            make_float4(s8[r][0], s8[r][1], s8[r][2], s8[r][3]);
        *(float4*)&sc[rq * 516 + 256 + kg * 4] =
            make_float4(s8[r][4], s8[r][5], s8[r][6], s8[r][7]);
      }
    }
    __syncthreads();

    // stage FULL VP panel
#pragma unroll 8
    for (int u = 0; u < 16; ++u) {
      const int r = srow + 32 * u;
      float4 v = *(const float4*)(vp + ((size_t)(b * 512 + r)) * 256 + h * 32 + scol4);
      *(float4*)KB4(kb, r, scol4) = v;
    }
    __syncthreads();

    // Phase 3: 8q x 4a, 8-way k-split
    const int ag  = t & 7;
    const int qg3 = (t >> 3) & 3;
    const int ks  = t >> 5;
    float a3[8][4] = {};
#pragma unroll 2
    for (int g = 0; g < 16; ++g) {
      const int kbase = ks * 64 + g * 4;
      float4 sq[8], vf[4];
#pragma unroll
      for (int r = 0; r < 8; ++r)
        sq[r] = *(const float4*)&sc[(qg3 + 4 * r) * 516 + kbase];
#pragma unroll
      for (int c = 0; c < 4; ++c)
        vf[c] = *(const float4*)KB4(kb, kbase + c, ag * 4);
#pragma unroll
      for (int r = 0; r < 8; ++r) {
        a3[r][0] += sq[r].x * vf[0].x + sq[r].y * vf[1].x + sq[r].z * vf[2].x + sq[r].w * vf[3].x;
        a3[r][1] += sq[r].x * vf[0].y + sq[r].y * vf[1].y + sq[r].z * vf[2].y + sq[r].w * vf[3].y;
        a3[r][2] += sq[r].x * vf[0].z + sq[r].y * vf[1].z + sq[r].z * vf[2].z + sq[r].w * vf[3].z;
        a3[r][3] += sq[r].x * vf[0].w + sq[r].y * vf[1].w + sq[r].z * vf[2].w + sq[r].w * vf[3].w;
      }
    }
#pragma unroll
    for (int r = 0; r < 8; ++r)
#pragma unroll
      for (int c = 0; c < 4; ++c)
        a3[r][c] += __shfl_xor(a3[r][c], 32);
    __syncthreads();
    float* part = &kb[0];
    if ((t & 32) == 0) {
      const int w = t >> 6;
#pragma unroll
      for (int r = 0; r < 8; ++r)
#pragma unroll
        for (int c = 0; c < 4; ++c)
          part[w * 1152 + (qg3 + 4 * r) * 36 + ag * 4 + c] = a3[r][c];
    }
    __syncthreads();
    {
      const int q = t >> 3, a0 = (t & 7) << 2;
      const int d0 = h * 32 + a0;
      const float invT = 1.0f / red[q];
      float4 s0 = *(const float4*)&part[q * 36 + a0];
      float4 s1 = *(const float4*)&part[1152 + q * 36 + a0];
      float4 s2 = *(const float4*)&part[2304 + q * 36 + a0];
      float4 s3 = *(const float4*)&part[3456 + q * 36 + a0];
      const float4 pp = *(const float4*)(pw + d0);
      const float4 vr = *(const float4*)(vrangew + b * 256 + d0);
      const float4 vm = *(const float4*)(vminw + b * 256 + d0);
      float4 o;
      o.x = (expf(log1pf((s0.x + s1.x + s2.x + s3.x) * invT) / pp.x) - BCONST) * vr.x / ONE_MINUS_B + vm.x;
      o.y = (expf(log1pf((s0.y + s1.y + s2.y + s3.y) * invT) / pp.y) - BCONST) * vr.y / ONE_MINUS_B + vm.y;
      o.z = (expf(log1pf((s0.z + s1.z + s2.z + s3.z) * invT) / pp.z) - BCONST) * vr.z / ONE_MINUS_B + vm.z;
      o.w = (expf(log1pf((s0.w + s1.w + s2.w + s3.w) * invT) / pp.w) - BCONST) * vr.w / ONE_MINUS_B + vm.w;
      *(float4*)(ew + ((size_t)(b * 512 + q0g + q)) * 256 + d0) = o;
    }
  }
  gbar(ctr + 1, 256u);

  // ======== Phase D: output projection, 32x32 tile per block ========
  {
    float (*As)[36] = qs;                      // alias (phase C done)
    float (*Bs)[36] = (float(*)[36])&sc[0];
    const int i0 = (bid & 31) * 32;
    const int j0 = (bid >> 5) * 32;
    const int lr = t >> 3;
    const int lc = (t & 7) << 2;
    const int tx = t & 15, ty = t >> 4;
    const float* Bsrc = WOUT + (size_t)j0 * 256;

    float4 pa = *(const float4*)(ew + (size_t)(i0 + lr) * 256 + lc);
    float4 pb = *(const float4*)(Bsrc + (size_t)lr * 256 + lc);
    float acc[2][2] = {};
    for (int k0 = 0; k0 < 256; k0 += 32) {
      __syncthreads();
      *(float4*)&As[lr][lc] = pa;
      *(float4*)&Bs[lr][lc] = pb;
      __syncthreads();
      if (k0 + 32 < 256) {
        pa = *(const float4*)(ew + (size_t)(i0 + lr) * 256 + k0 + 32 + lc);
        pb = *(const float4*)(Bsrc + (size_t)lr * 256 + k0 + 32 + lc);
      }
#pragma unroll
      for (int kk = 0; kk < 32; kk += 4) {
        float4 af[2], bf[2];
#pragma unroll
        for (int r = 0; r < 2; ++r) af[r] = *(const float4*)&As[ty * 2 + r][kk];
#pragma unroll
        for (int c = 0; c < 2; ++c) bf[c] = *(const float4*)&Bs[tx + 16 * c][kk];
#pragma unroll
        for (int r = 0; r < 2; ++r)
#pragma unroll
          for (int c = 0; c < 2; ++c)
            acc[r][c] += af[r].x * bf[c].x + af[r].y * bf[c].y +
                         af[r].z * bf[c].z + af[r].w * bf[c].w;
      }
    }
#pragma unroll
    for (int r = 0; r < 2; ++r)
#pragma unroll
      for (int c = 0; c < 2; ++c)
        out[(size_t)(i0 + ty * 2 + r) * 256 + j0 + tx + 16 * c] = acc[r][c];
  }
}

// ---------------------------------------------------------------------------
extern "C" void kernel_launch(void* const* d_in, const int* in_sizes, int n_in,
                              void* d_out, int out_size, void* d_ws, size_t ws_size,
                              hipStream_t stream) {
  const float* ctx  = (const float*)d_in[0];
  const float* WQ   = (const float*)d_in[1];
  const float* WKV  = (const float*)d_in[2];
  const float* WOUT = (const float*)d_in[3];
  const float* PP   = (const float*)d_in[4];
  float* ws      = (float*)d_ws;
  float* qkv     = ws + OFF_QKV;
  float* vp      = ws + OFF_VP;
  float* ew      = ws + OFF_EW;
  float* pminP   = ws + OFF_PMIN;
  float* pmaxP   = ws + OFF_PMAX;
  float* vminw   = ws + OFF_VMIN;
  float* vrangew = ws + OFF_VRANGE;
  float* pw      = ws + OFF_P;
  unsigned int* ctr = (unsigned int*)(ws + OFF_CTR);
  float* out     = (float*)d_out;

  // zero the two barrier counters (ws is 0xAA-poisoned before each launch)
  hipMemsetAsync(ctr, 0, 2 * sizeof(unsigned int), stream);

  // Fused Q|K|V projection + V min/max partials (R12-proven config)
  gemm_qkv<<<dim3(32, 12), 256, 0, stream>>>(
      ctx, WQ, WKV, 256, qkv, 768, 256, 256, pminP, pmaxP);

  // vpk -> barrier -> attention -> barrier -> output projection
  mega<<<256, 256, 0, stream>>>(
      qkv, pminP, pmaxP, PP, vp, vminw, vrangew, pw, ew, WOUT, out, ctr);
}

// Round 15
// 108.033 us; speedup vs baseline: 1.3014x; 1.3014x over previous
//
#include <hip/hip_runtime.h>
#include <math.h>

// Problem constants
#define DD 256
#define HH 8
#define AA 32
#define SS 512
#define BB 2
constexpr float BCONST      = 0.9f;
constexpr float ONE_MINUS_B = 0.1f;
constexpr float EPSF        = 1e-10f;
constexpr float SCALEF      = 0.0625f;   // 1/sqrt(256), exact power of 2
constexpr float FLTMAX      = 3.402823466e38f;

// Workspace layout (float offsets)
#define OFF_QKV    0
#define OFF_VP     786432
#define OFF_EW     1048576
#define OFF_PMIN   1310720
#define OFF_PMAX   1318912
#define OFF_VMIN   1327104
#define OFF_VRANGE 1327616
#define OFF_P      1328128

// Swizzled chunk buffer: row-major LD=32 floats, bank-quad ^= (row>>2)&7.
#define KB4(buf, row, col4) \
  (&(buf)[((row) << 5) | ((((col4) >> 2) ^ (((row) >> 2) & 7)) << 2)])

// ---------------------------------------------------------------------------
// Tiled fp32 GEMM (R9/R12 config — empirical best across R7/R9/R10/R11/R13):
// C[i][j] = dot(A[i,:K], Brow(j)).
// MM=true: V-column blocks also write per-row-tile min/max partials.
// ---------------------------------------------------------------------------
template<int TM, int TN, int RM, int RN, bool MM>
__global__ __launch_bounds__(256) void gemm_t(
    const float* __restrict__ A, const float* __restrict__ B0,
    const float* __restrict__ B1, int nsplit,
    float* __restrict__ C, int ldc, int K, int lda,
    float* __restrict__ pminP, float* __restrict__ pmaxP) {
  constexpr int LDT = 36;
  constexpr int CG  = TN / RN;
  constexpr int NA  = TM * 32 / 1024;
  constexpr int NB  = TN * 32 / 1024;
  __shared__ float As[TM][LDT];
  __shared__ float Bs[TN][LDT];
  const int i0 = blockIdx.x * TM;
  const int j0 = blockIdx.y * TN;
  const float* Bsrc = (j0 < nsplit) ? (B0 + (size_t)j0 * K)
                                    : (B1 + (size_t)(j0 - nsplit) * K);
  const int t  = threadIdx.x;
  const int lr = t >> 3;
  const int lc = (t & 7) << 2;
  const int tx = t % CG, ty = t / CG;

  float4 pa[NA], pb[NB];
#pragma unroll
  for (int u = 0; u < NA; ++u)
    pa[u] = *(const float4*)(A + (size_t)(i0 + lr + 32 * u) * lda + lc);
#pragma unroll
  for (int u = 0; u < NB; ++u)
    pb[u] = *(const float4*)(Bsrc + (size_t)(lr + 32 * u) * K + lc);

  float acc[RM][RN] = {};
  for (int k0 = 0; k0 < K; k0 += 32) {
    __syncthreads();
#pragma unroll
    for (int u = 0; u < NA; ++u) *(float4*)&As[lr + 32 * u][lc] = pa[u];
#pragma unroll
    for (int u = 0; u < NB; ++u) *(float4*)&Bs[lr + 32 * u][lc] = pb[u];
    __syncthreads();
    if (k0 + 32 < K) {
#pragma unroll
      for (int u = 0; u < NA; ++u)
        pa[u] = *(const float4*)(A + (size_t)(i0 + lr + 32 * u) * lda + k0 + 32 + lc);
#pragma unroll
      for (int u = 0; u < NB; ++u)
        pb[u] = *(const float4*)(Bsrc + (size_t)(lr + 32 * u) * K + k0 + 32 + lc);
    }
#pragma unroll
    for (int kk = 0; kk < 32; kk += 4) {
      float4 af[RM], bf[RN];
#pragma unroll
      for (int r = 0; r < RM; ++r) af[r] = *(const float4*)&As[ty * RM + r][kk];
#pragma unroll
      for (int c = 0; c < RN; ++c) bf[c] = *(const float4*)&Bs[tx + CG * c][kk];
#pragma unroll
      for (int r = 0; r < RM; ++r)
#pragma unroll
        for (int c = 0; c < RN; ++c)
          acc[r][c] += af[r].x * bf[c].x + af[r].y * bf[c].y +
                       af[r].z * bf[c].z + af[r].w * bf[c].w;
    }
  }
#pragma unroll
  for (int r = 0; r < RM; ++r)
#pragma unroll
    for (int c = 0; c < RN; ++c)
      C[(size_t)(i0 + ty * RM + r) * ldc + j0 + tx + CG * c] = acc[r][c];

  if (MM && j0 >= 512) {
    __syncthreads();
    float* mnb = &As[0][0];
    float* mxb = &Bs[0][0];
#pragma unroll
    for (int c = 0; c < RN; ++c) {
      float mn = acc[0][c], mx = acc[0][c];
#pragma unroll
      for (int r = 1; r < RM; ++r) {
        mn = fminf(mn, acc[r][c]);
        mx = fmaxf(mx, acc[r][c]);
      }
      mnb[(tx + CG * c) * 17 + ty] = mn;
      mxb[(tx + CG * c) * 17 + ty] = mx;
    }
    __syncthreads();
    if (t < TN) {
      float mn = mnb[t * 17], mx = mxb[t * 17];
#pragma unroll
      for (int i = 1; i < 16; ++i) {
        mn = fminf(mn, mnb[t * 17 + i]);
        mx = fmaxf(mx, mxb[t * 17 + i]);
      }
      const int bx = i0 >> 5;          // row-tile 0..31 (16 per batch @ TM=32)
      pminP[bx * 256 + (j0 - 512) + t] = mn;
      pmaxP[bx * 256 + (j0 - 512) + t] = mx;
    }
  }
}

// ---------------------------------------------------------------------------
// vp = expm1(p * log(v_norm)); also vmin / vrange per (b,d) and pw.
// 16 row-tile partials per batch (TM=32 in QKV).
// ---------------------------------------------------------------------------
__global__ __launch_bounds__(256) void vpk(
    const float* __restrict__ qkv, const float* __restrict__ pminP,
    const float* __restrict__ pmaxP, const float* __restrict__ p_param,
    float* __restrict__ vp, float* __restrict__ vminw,
    float* __restrict__ vrangew, float* __restrict__ pw) {
  const int blk = blockIdx.x;           // 0..1023
  const int b = blk >> 9, s = blk & 511;
  const int d = threadIdx.x;
  float mn = pminP[(b * 16) * 256 + d];
  float mx = pmaxP[(b * 16) * 256 + d];
#pragma unroll
  for (int c = 1; c < 16; ++c) {
    mn = fminf(mn, pminP[(b * 16 + c) * 256 + d]);
    mx = fmaxf(mx, pmaxP[(b * 16 + c) * 256 + d]);
  }
  float p = 50000.0f * tanhf(0.005f * p_param[d]) + 1.0f;
  if (p == 0.0f) p = 0.0001f;
  const float range = mx - mn + EPSF;
  const float v  = qkv[((size_t)(b * 512 + s)) * 768 + 512 + d];
  const float vn = (ONE_MINUS_B * (v - mn)) / range + BCONST;
  vp[(size_t)blk * 256 + d] = expm1f(p * logf(vn));
  if (s == 0) { vminw[b * 256 + d] = mn; vrangew[b * 256 + d] = range; }
  if (blk == 0) pw[d] = p;
}

// ---------------------------------------------------------------------------
// Fused attention (R12-proven): 32q/block, full 512-k panel, LDS-lean
// 8qx8k / 8qx4a micro-tiles, inline softmax (no max subtraction; scores
// |s| < ~3 vs fp32 exp overflow at 88; exp(s)/T mathematically identical),
// wave-butterfly row sums. grid = (S/32, B*H); 256 threads; 1 block/CU.
// ---------------------------------------------------------------------------
__global__ __launch_bounds__(256) void attn_k(
    const float* __restrict__ qkv, const float* __restrict__ vp,
    const float* __restrict__ pw, const float* __restrict__ vminw,
    const float* __restrict__ vrangew, float* __restrict__ ew) {
  __shared__ float qs[32][36];
  __shared__ float sc[32 * 516];       // [q][k] unnormalized softmax e
  __shared__ float kb[512 * 32];       // swizzled K / VP panel (reused: part)
  __shared__ float red[32];            // per-row sum T
  const int bh  = blockIdx.y;
  const int b   = bh >> 3, h = bh & 7;
  const int q0g = blockIdx.x * 32;
  const int t   = threadIdx.x;
  const int srow = t >> 3, scol4 = (t & 7) << 2;

  // q tile (32 x 32), fold in SCALE (exact *2^-4)
  {
    const int q = t >> 3, c4 = (t & 7) << 2;
    float4 qv = *(const float4*)(qkv + ((size_t)(b * 512 + q0g + q)) * 768 + h * 32 + c4);
    qv.x *= SCALEF; qv.y *= SCALEF; qv.z *= SCALEF; qv.w *= SCALEF;
    *(float4*)&qs[q][c4] = qv;
  }
  // stage FULL K panel (512 rows)
#pragma unroll 8
  for (int u = 0; u < 16; ++u) {
    const int r = srow + 32 * u;
    float4 v = *(const float4*)(qkv + ((size_t)(b * 512 + r)) * 768 + 256 + h * 32 + scol4);
    *(float4*)KB4(kb, r, scol4) = v;
  }
  __syncthreads();

  // ---- Phase 1: scores + inline softmax. thread = 8q (qgw+4r) x 8k.
  {
    const int qgw = t >> 6;            // wave id: wave-uniform q group
    const int kg  = t & 63;            // k cols kg*4..+3 and 256+kg*4..+3
    float s8[8][8] = {};
#pragma unroll 2
    for (int kk = 0; kk < 32; kk += 4) {
      float4 qf[8], kf1[4], kf2[4];
#pragma unroll
      for (int r = 0; r < 8; ++r) qf[r] = *(const float4*)&qs[qgw + 4 * r][kk];
#pragma unroll
      for (int c = 0; c < 4; ++c) {
        kf1[c] = *(const float4*)KB4(kb, kg * 4 + c, kk);
        kf2[c] = *(const float4*)KB4(kb, 256 + kg * 4 + c, kk);
      }
#pragma unroll
      for (int r = 0; r < 8; ++r)
#pragma unroll
        for (int c = 0; c < 4; ++c) {
          s8[r][c]     += qf[r].x * kf1[c].x + qf[r].y * kf1[c].y +
                          qf[r].z * kf1[c].z + qf[r].w * kf1[c].w;
          s8[r][4 + c] += qf[r].x * kf2[c].x + qf[r].y * kf2[c].y +
                          qf[r].z * kf2[c].z + qf[r].w * kf2[c].w;
        }
    }
    float rs[8];
#pragma unroll
    for (int r = 0; r < 8; ++r) {
      float s = 0.f;
#pragma unroll
      for (int c = 0; c < 8; ++c) {
        s8[r][c] = __expf(s8[r][c]);
        s += s8[r][c];
      }
      rs[r] = s;
    }
#pragma unroll
    for (int m = 1; m < 64; m <<= 1)
#pragma unroll
      for (int r = 0; r < 8; ++r) rs[r] += __shfl_xor(rs[r], m);
    if ((t & 63) == 0)
#pragma unroll
      for (int r = 0; r < 8; ++r) red[qgw + 4 * r] = rs[r];
#pragma unroll
    for (int r = 0; r < 8; ++r) {
      const int rq = qgw + 4 * r;
      *(float4*)&sc[rq * 516 + kg * 4] =
          make_float4(s8[r][0], s8[r][1], s8[r][2], s8[r][3]);
      *(float4*)&sc[rq * 516 + 256 + kg * 4] =
          make_float4(s8[r][4], s8[r][5], s8[r][6], s8[r][7]);
    }
  }
  __syncthreads();                     // sc/red done; kb K-reads done

  // ---- stage FULL VP panel into kb
#pragma unroll 8
  for (int u = 0; u < 16; ++u) {
    const int r = srow + 32 * u;
    float4 v = *(const float4*)(vp + ((size_t)(b * 512 + r)) * 256 + h * 32 + scol4);
    *(float4*)KB4(kb, r, scol4) = v;
  }
  __syncthreads();

  // ---- Phase 3: ACC[q][a] = sum_k e[q][k]*vp[k][a]; thread = 8q x 4a,
  // 8-way k-split (64 k per slice).
  const int ag  = t & 7;               // a cols ag*4..+3
  const int qg3 = (t >> 3) & 3;        // q rows qg3+4r
  const int ks  = t >> 5;              // 0..7
  float a3[8][4] = {};
#pragma unroll 2
  for (int g = 0; g < 16; ++g) {
    const int kbase = ks * 64 + g * 4;
    float4 sq[8], vf[4];
#pragma unroll
    for (int r = 0; r < 8; ++r)
      sq[r] = *(const float4*)&sc[(qg3 + 4 * r) * 516 + kbase];
#pragma unroll
    for (int c = 0; c < 4; ++c)
      vf[c] = *(const float4*)KB4(kb, kbase + c, ag * 4);
#pragma unroll
    for (int r = 0; r < 8; ++r) {
      a3[r][0] += sq[r].x * vf[0].x + sq[r].y * vf[1].x + sq[r].z * vf[2].x + sq[r].w * vf[3].x;
      a3[r][1] += sq[r].x * vf[0].y + sq[r].y * vf[1].y + sq[r].z * vf[2].y + sq[r].w * vf[3].y;
      a3[r][2] += sq[r].x * vf[0].z + sq[r].y * vf[1].z + sq[r].z * vf[2].z + sq[r].w * vf[3].z;
      a3[r][3] += sq[r].x * vf[0].w + sq[r].y * vf[1].w + sq[r].z * vf[2].w + sq[r].w * vf[3].w;
    }
  }

  // ---- fold ks pair within wave (wave w holds ks = 2w, 2w+1)
#pragma unroll
  for (int r = 0; r < 8; ++r)
#pragma unroll
    for (int c = 0; c < 4; ++c)
      a3[r][c] += __shfl_xor(a3[r][c], 32);
  __syncthreads();                     // kb reads done; reuse as part
  float* part = &kb[0];                // [w4][32*36]
  if ((t & 32) == 0) {
    const int w = t >> 6;
#pragma unroll
    for (int r = 0; r < 8; ++r)
#pragma unroll
      for (int c = 0; c < 4; ++c)
        part[w * 1152 + (qg3 + 4 * r) * 36 + ag * 4 + c] = a3[r][c];
  }
  __syncthreads();

  // ---- final 4-wave reduction + robust power-mean epilogue (4 outputs/thr)
  {
    const int q = t >> 3, a0 = (t & 7) << 2;
    const int d0 = h * 32 + a0;
    const float invT = 1.0f / red[q];
    float4 s0 = *(const float4*)&part[q * 36 + a0];
    float4 s1 = *(const float4*)&part[1152 + q * 36 + a0];
    float4 s2 = *(const float4*)&part[2304 + q * 36 + a0];
    float4 s3 = *(const float4*)&part[3456 + q * 36 + a0];
    const float4 pp = *(const float4*)(pw + d0);
    const float4 vr = *(const float4*)(vrangew + b * 256 + d0);
    const float4 vm = *(const float4*)(vminw + b * 256 + d0);
    float4 o;
    o.x = (expf(log1pf((s0.x + s1.x + s2.x + s3.x) * invT) / pp.x) - BCONST) * vr.x / ONE_MINUS_B + vm.x;
    o.y = (expf(log1pf((s0.y + s1.y + s2.y + s3.y) * invT) / pp.y) - BCONST) * vr.y / ONE_MINUS_B + vm.y;
    o.z = (expf(log1pf((s0.z + s1.z + s2.z + s3.z) * invT) / pp.z) - BCONST) * vr.z / ONE_MINUS_B + vm.z;
    o.w = (expf(log1pf((s0.w + s1.w + s2.w + s3.w) * invT) / pp.w) - BCONST) * vr.w / ONE_MINUS_B + vm.w;
    *(float4*)(ew + ((size_t)(b * 512 + q0g + q)) * 256 + d0) = o;
  }
}

// ---------------------------------------------------------------------------
extern "C" void kernel_launch(void* const* d_in, const int* in_sizes, int n_in,
                              void* d_out, int out_size, void* d_ws, size_t ws_size,
                              hipStream_t stream) {
  const float* ctx  = (const float*)d_in[0];
  const float* WQ   = (const float*)d_in[1];
  const float* WKV  = (const float*)d_in[2];
  const float* WOUT = (const float*)d_in[3];
  const float* PP   = (const float*)d_in[4];
  float* ws      = (float*)d_ws;
  float* qkv     = ws + OFF_QKV;
  float* vp      = ws + OFF_VP;
  float* ew      = ws + OFF_EW;
  float* pminP   = ws + OFF_PMIN;
  float* pmaxP   = ws + OFF_PMAX;
  float* vminw   = ws + OFF_VMIN;
  float* vrangew = ws + OFF_VRANGE;
  float* pw      = ws + OFF_P;
  float* out     = (float*)d_out;

  // Fused Q|K|V projection + V min/max partials: 1024x768x256, 32x64 tiles
  gemm_t<32, 64, 2, 4, true><<<dim3(32, 12), 256, 0, stream>>>(
      ctx, WQ, WKV, 256, qkv, 768, 256, 256, pminP, pmaxP);
  // expm1(p * log(v_norm)) + p vector + vmin/vrange (16 partials/batch)
  vpk<<<1024, 256, 0, stream>>>(qkv, pminP, pmaxP, PP, vp, vminw, vrangew, pw);
  // Fused attention + inline softmax + power-mean epilogue
  attn_k<<<dim3(16, 16), 256, 0, stream>>>(qkv, vp, pw, vminw, vrangew, ew);
  // Output projection: 1024x256x256, 32x32 tiles (256 blocks)
  gemm_t<32, 32, 2, 2, false><<<dim3(32, 8), 256, 0, stream>>>(
      ew, WOUT, WOUT, 1 << 30, out, 256, 256, 256, nullptr, nullptr);
}